// Round 1
// baseline (341.893 us; speedup 1.0000x reference)
//
#include <hip/hip_runtime.h>
#include <hip/hip_bf16.h>
#include <cstdint>
#include <cstddef>

// Problem constants (fixed by the reference)
#define TDIM 1024
#define HDIM 1024
#define FDIM 2048
#define NEXP 8
#define NENT 2048   // T * K

typedef __bf16 bf16_t;
typedef __bf16 bf16x4 __attribute__((ext_vector_type(4)));
typedef __bf16 bf16x8 __attribute__((ext_vector_type(8)));
typedef float  f32x4  __attribute__((ext_vector_type(4)));

#define H_ELEMS ((size_t)TDIM*HDIM)   // 1048576

// ---------------- workspace layout (bytes) ----------------
#define WB_OFFSETS 0                                   // int[16]
#define WB_ETOK    64
#define WB_ESCALE  (WB_ETOK + NENT*4)
#define WB_ACT     16512                               // bf16[NENT][FDIM] = 8 MB
#define WB_H       (WB_ACT + (size_t)NENT*FDIM*2)      // bf16[T][H] = 2 MB

__device__ __forceinline__ void gload16(const void* g, void* l) {
  __builtin_amdgcn_global_load_lds((const __attribute__((address_space(1))) void*)g,
                                   (__attribute__((address_space(3))) void*)l, 16, 0, 0);
}

__device__ __forceinline__ bf16x8 cvt8(const float4 a, const float4 b) {
  bf16x8 o;
  o[0]=(bf16_t)a.x; o[1]=(bf16_t)a.y; o[2]=(bf16_t)a.z; o[3]=(bf16_t)a.w;
  o[4]=(bf16_t)b.x; o[5]=(bf16_t)b.y; o[6]=(bf16_t)b.z; o[7]=(bf16_t)b.w;
  return o;
}

// 3-bit bank swizzle: seg position = seg ^ (row&3) ^ ((row>>2)&3).
// Old 2-bit version left rows {r,r+4,r+8,r+12} on the same bank group
// (64B row pitch -> only row&1 reaches the bank bits) = 4-way conflict on
// every frag ds_read_b128. With the extra (row>>2) term, the 16 rows of a
// fragment read map 2-per-bank-group (2-way aliasing = free, m136).
__device__ __forceinline__ int segswz(int seg, int row) {
  return seg ^ (row & 3) ^ ((row >> 2) & 3);
}

// ---------------- routing (single block, one launch) ----------------
__global__ void route_all(const int* __restrict__ sel, const float* __restrict__ scal,
                          int* __restrict__ offsets, int* __restrict__ etok,
                          float* __restrict__ escale) {
  __shared__ int cnt[NEXP], cnt2[NEXP], offs[NEXP+1];
  const int t = threadIdx.x;    // 256 threads, 8 entries each
  if (t < NEXP) { cnt[t] = 0; cnt2[t] = 0; }
  __syncthreads();
  int e8[8];
  #pragma unroll
  for (int q = 0; q < 8; q++) {
    int i = t*8 + q;
    e8[q] = sel[i];
    atomicAdd(&cnt[e8[q]], 1);
  }
  __syncthreads();
  if (t == 0) {
    int s = 0;
    for (int e = 0; e < NEXP; e++) { offs[e] = s; offsets[e] = s; s += cnt[e]; }
    offs[NEXP] = s; offsets[NEXP] = s;
  }
  __syncthreads();
  #pragma unroll
  for (int q = 0; q < 8; q++) {
    int i = t*8 + q;
    int e = e8[q];
    int pos = offs[e] + atomicAdd(&cnt2[e], 1);
    etok[pos]   = i >> 1;       // TOPK == 2
    escale[pos] = scal[i];
  }
}

// ---------------- hidden fp32 -> bf16 ----------------
__global__ void convert_h(const float* __restrict__ h, bf16_t* __restrict__ hbf) {
  size_t idx = ((size_t)blockIdx.x*256 + threadIdx.x) * 8;
  float4 v0 = ((const float4*)(h + idx))[0];
  float4 v1 = ((const float4*)(h + idx))[1];
  *(bf16x8*)(hbf + idx) = cvt8(v0, v1);
}

// ======== pipelined grouped GEMMs (T3+T4: dbuf LDS, 1 barrier/K-step, ========
// ======== counted vmcnt — A-load latency hidden under the MFMA phase) ========
//
// Steady-state step for tile t (buffer CUR holds tile t, regs hold B(t+1)):
//   ds_write B(t+1) -> B[CUR^1]         (compiler drains the 4 B reg loads)
//   global_load_lds A(t+1) -> As[CUR^1] (2 vm ops)
//   load B(t+2) -> regs                 (4 vm ops, stay in flight past barrier)
//   ds_read frags[CUR]; 16x MFMA        (overlaps the 6 outstanding vm ops)
//   s_waitcnt vmcnt(4) lgkmcnt(0)       (A(t+1) done; B(t+2) NOT drained)
//   s_barrier
// sched_barrier(0) pins each boundary so the hand-counted vmcnt is valid.

// GEMM1: act = silu(x@w1g^T + b1g) * (x@w1l^T + b1l)
__global__ __launch_bounds__(256, 3) void gemm1_v6(
    const bf16_t* __restrict__ hbf, const float* __restrict__ w1,
    const float* __restrict__ b1, const int* __restrict__ offsets,
    const int* __restrict__ etok, bf16_t* __restrict__ act)
{
  const int e   = blockIdx.z;
  const int off = offsets[e];
  const int nt  = offsets[e+1] - off;
  const int m0  = blockIdx.y * 128;
  if (m0 >= nt) return;
  const int n0  = blockIdx.x * 64;

  __shared__ __align__(16) bf16_t As[2][128*32];
  __shared__ __align__(16) bf16_t Bg[2][64*32];
  __shared__ __align__(16) bf16_t Bl[2][64*32];

  const int tid  = threadIdx.x;
  const int w    = tid >> 6, lane = tid & 63;
  const int quad = lane >> 4, lr = lane & 15;
  const int wm   = w >> 1,  wn = w & 1;

  // ---- A staging: wave w, inst i covers LDS rows [i*64 + w*16, +16) ----
  const bf16_t* asrc0; const bf16_t* asrc1;
  int arow0, arow1;
  {
    const int r0 = 0*64 + w*16 + (lane >> 2);
    const int r1 = 1*64 + w*16 + (lane >> 2);
    const int s0 = segswz(lane & 3, r0);
    const int s1 = segswz(lane & 3, r1);
    int e0 = m0 + r0; if (e0 > nt-1) e0 = nt-1;   // clamp; masked in epilogue
    int e1 = m0 + r1; if (e1 > nt-1) e1 = nt-1;
    asrc0 = hbf + (size_t)etok[off + e0]*HDIM + s0*8;
    asrc1 = hbf + (size_t)etok[off + e1]*HDIM + s1*8;
    arow0 = (0*64 + w*16)*32;                     // + lane*16B implicit
    arow1 = (1*64 + w*16)*32;
  }

  // ---- B staging: thread t -> row t>>2 (0..63), seg t&3 ----
  const int br = tid >> 2, bs = tid & 3;
  const float* gsrc = w1 + ((size_t)e*2*FDIM + (size_t)(n0 + br))*HDIM + bs*8;
  const float* lsrc = gsrc + (size_t)FDIM*HDIM;
  const int bofs = br*32 + (segswz(bs, br) << 3);

  // ---- loop-invariant fragment LDS offsets ----
  int aoff[4], boff[2];
  #pragma unroll
  for (int i = 0; i < 4; i++) {
    const int r = wm*64 + i*16 + lr;
    aoff[i] = r*32 + (segswz(quad, r) << 3);
  }
  #pragma unroll
  for (int j = 0; j < 2; j++) {
    const int r = wn*32 + j*16 + lr;
    boff[j] = r*32 + (segswz(quad, r) << 3);
  }

  f32x4 accg[4][2] = {}, accl[4][2] = {};
  float4 g4[2], l4[2];

#define G1_LOADB(K0)                                                          \
  { const float4* p_ = (const float4*)(gsrc + (K0)); g4[0]=p_[0]; g4[1]=p_[1];\
    const float4* q_ = (const float4*)(lsrc + (K0)); l4[0]=q_[0]; l4[1]=q_[1]; }

#define G1_STAGE(K0, NXT)                                                     \
  { *(bf16x8*)&Bg[NXT][bofs] = cvt8(g4[0], g4[1]);                            \
    *(bf16x8*)&Bl[NXT][bofs] = cvt8(l4[0], l4[1]);                            \
    __builtin_amdgcn_sched_barrier(0);                                        \
    gload16(asrc0 + (K0), &As[NXT][arow0]);                                   \
    gload16(asrc1 + (K0), &As[NXT][arow1]);                                   \
    __builtin_amdgcn_sched_barrier(0); }

#define G1_MFMA(CUR)                                                          \
  { bf16x8 af[4], gf[2], lf[2];                                               \
    _Pragma("unroll")                                                         \
    for (int i = 0; i < 4; i++) af[i] = *(const bf16x8*)&As[CUR][aoff[i]];    \
    _Pragma("unroll")                                                         \
    for (int j = 0; j < 2; j++) {                                             \
      gf[j] = *(const bf16x8*)&Bg[CUR][boff[j]];                              \
      lf[j] = *(const bf16x8*)&Bl[CUR][boff[j]];                              \
    }                                                                         \
    _Pragma("unroll")                                                         \
    for (int i = 0; i < 4; i++)                                               \
      _Pragma("unroll")                                                       \
      for (int j = 0; j < 2; j++) {                                           \
        accg[i][j] = __builtin_amdgcn_mfma_f32_16x16x32_bf16(af[i], gf[j], accg[i][j], 0, 0, 0); \
        accl[i][j] = __builtin_amdgcn_mfma_f32_16x16x32_bf16(af[i], lf[j], accl[i][j], 0, 0, 0); \
      } }

  // ---- prologue: stage tile 0 into buf0, prefetch B(1) ----
  G1_LOADB(0);                                   // 4 vm
  __builtin_amdgcn_sched_barrier(0);
  gload16(asrc0 + 0, &As[0][arow0]);             // 2 vm
  gload16(asrc1 + 0, &As[0][arow1]);
  __builtin_amdgcn_sched_barrier(0);
  *(bf16x8*)&Bg[0][bofs] = cvt8(g4[0], g4[1]);   // compiler drains B(0) regs
  *(bf16x8*)&Bl[0][bofs] = cvt8(l4[0], l4[1]);
  G1_LOADB(32);                                  // 4 vm (B(1))
  asm volatile("s_waitcnt vmcnt(4) lgkmcnt(0)" ::: "memory");  // A(0) done
  __builtin_amdgcn_sched_barrier(0);
  __builtin_amdgcn_s_barrier();
  __builtin_amdgcn_sched_barrier(0);

#define G1_STEP_FULL(CUR)                                                     \
  { G1_STAGE(k0 + 32, (CUR)^1);                                               \
    G1_LOADB(k0 + 64);                                                        \
    __builtin_amdgcn_sched_barrier(0);                                        \
    G1_MFMA(CUR);                                                             \
    asm volatile("s_waitcnt vmcnt(4) lgkmcnt(0)" ::: "memory");               \
    __builtin_amdgcn_sched_barrier(0);                                        \
    __builtin_amdgcn_s_barrier();                                             \
    __builtin_amdgcn_sched_barrier(0);                                        \
    k0 += 32; }

  int k0 = 0;
  while (k0 < HDIM - 64) {        // t = 0..29: always another B(k0+64) to load
    G1_STEP_FULL(0);
    G1_STEP_FULL(1);
  }
  // k0 == 960: stage last tile (992 -> buf1), no more B loads
  G1_STAGE(992, 1);
  __builtin_amdgcn_sched_barrier(0);
  G1_MFMA(0);
  asm volatile("s_waitcnt vmcnt(0) lgkmcnt(0)" ::: "memory");
  __builtin_amdgcn_sched_barrier(0);
  __builtin_amdgcn_s_barrier();
  __builtin_amdgcn_sched_barrier(0);
  G1_MFMA(1);

#undef G1_STEP_FULL
#undef G1_MFMA
#undef G1_STAGE
#undef G1_LOADB

  // epilogue: bias + silu(gate)*lin -> act (bf16)
  #pragma unroll
  for (int j = 0; j < 2; j++) {
    const int f = n0 + wn*32 + j*16 + lr;
    const float bg_ = b1[e*2*FDIM + f];
    const float bl_ = b1[e*2*FDIM + FDIM + f];
    #pragma unroll
    for (int i = 0; i < 4; i++) {
      #pragma unroll
      for (int r = 0; r < 4; r++) {
        const int m = wm*64 + i*16 + quad*4 + r;
        if (m0 + m < nt) {
          const float g = accg[i][j][r] + bg_;
          const float l = accl[i][j][r] + bl_;
          const float s = g / (1.f + __expf(-g)) * l;
          act[(size_t)(off + m0 + m)*FDIM + f] = (bf16_t)s;
        }
      }
    }
  }
}

// GEMM2: y = act @ w2^T + b2; out[token] += scale * y  (atomic, split-K x4)
__global__ __launch_bounds__(256, 3) void gemm2_v6(
    const bf16_t* __restrict__ act, const float* __restrict__ w2,
    const float* __restrict__ b2, const int* __restrict__ offsets,
    const int* __restrict__ etok, const float* __restrict__ escale,
    float* __restrict__ out)
{
  const int e   = blockIdx.z;
  const int off = offsets[e];
  const int nt  = offsets[e+1] - off;
  const int m0  = blockIdx.y * 128;
  if (m0 >= nt) return;
  const int n0  = (blockIdx.x >> 2) * 128;
  const int kc  = blockIdx.x & 3;
  const int kbeg = kc * (FDIM/4);          // 512-chunk, 16 iters

  __shared__ __align__(16) bf16_t As[2][128*32];
  __shared__ __align__(16) bf16_t Bs[2][128*32];

  const int tid  = threadIdx.x;
  const int w    = tid >> 6, lane = tid & 63;
  const int quad = lane >> 4, lr = lane & 15;
  const int wm   = w >> 1,  wn = w & 1;

  const bf16_t* asrc0; const bf16_t* asrc1;
  int arow0, arow1;
  {
    const int r0 = 0*64 + w*16 + (lane >> 2);
    const int r1 = 1*64 + w*16 + (lane >> 2);
    const int s0 = segswz(lane & 3, r0);
    const int s1 = segswz(lane & 3, r1);
    int e0 = m0 + r0; if (e0 > nt-1) e0 = nt-1;
    int e1 = m0 + r1; if (e1 > nt-1) e1 = nt-1;
    asrc0 = act + (size_t)(off + e0)*FDIM + kbeg + s0*8;
    asrc1 = act + (size_t)(off + e1)*FDIM + kbeg + s1*8;
    arow0 = (0*64 + w*16)*32;
    arow1 = (1*64 + w*16)*32;
  }

  // B staging: thread t -> row t>>1 (0..127), col-half t&1 (segs 2c, 2c+1)
  const int br = tid >> 1, bc = tid & 1;
  const float* bsrc = w2 + ((size_t)e*HDIM + (size_t)(n0 + br))*FDIM + kbeg + bc*16;
  const int bofs0 = br*32 + (segswz(2*bc,   br) << 3);
  const int bofs1 = br*32 + (segswz(2*bc+1, br) << 3);

  int aoff[4], boff[4];
  #pragma unroll
  for (int i = 0; i < 4; i++) {
    const int r = wm*64 + i*16 + lr;
    aoff[i] = r*32 + (segswz(quad, r) << 3);
  }
  #pragma unroll
  for (int j = 0; j < 4; j++) {
    const int r = wn*64 + j*16 + lr;
    boff[j] = r*32 + (segswz(quad, r) << 3);
  }

  f32x4 acc[4][4] = {};
  float4 b4[4];

#define G2_LOADB(K0)                                                          \
  { const float4* p_ = (const float4*)(bsrc + (K0));                          \
    b4[0]=p_[0]; b4[1]=p_[1]; b4[2]=p_[2]; b4[3]=p_[3]; }

#define G2_STAGE(K0, NXT)                                                     \
  { *(bf16x8*)&Bs[NXT][bofs0] = cvt8(b4[0], b4[1]);                           \
    *(bf16x8*)&Bs[NXT][bofs1] = cvt8(b4[2], b4[3]);                           \
    __builtin_amdgcn_sched_barrier(0);                                        \
    gload16(asrc0 + (K0), &As[NXT][arow0]);                                   \
    gload16(asrc1 + (K0), &As[NXT][arow1]);                                   \
    __builtin_amdgcn_sched_barrier(0); }

#define G2_MFMA(CUR)                                                          \
  { bf16x8 af[4], bfr[4];                                                     \
    _Pragma("unroll")                                                         \
    for (int i = 0; i < 4; i++) af[i] = *(const bf16x8*)&As[CUR][aoff[i]];    \
    _Pragma("unroll")                                                         \
    for (int j = 0; j < 4; j++) bfr[j] = *(const bf16x8*)&Bs[CUR][boff[j]];   \
    _Pragma("unroll")                                                         \
    for (int i = 0; i < 4; i++)                                               \
      _Pragma("unroll")                                                       \
      for (int j = 0; j < 4; j++)                                             \
        acc[i][j] = __builtin_amdgcn_mfma_f32_16x16x32_bf16(af[i], bfr[j], acc[i][j], 0, 0, 0); }

  // ---- prologue ----
  G2_LOADB(0);                                   // 4 vm
  __builtin_amdgcn_sched_barrier(0);
  gload16(asrc0 + 0, &As[0][arow0]);             // 2 vm
  gload16(asrc1 + 0, &As[0][arow1]);
  __builtin_amdgcn_sched_barrier(0);
  *(bf16x8*)&Bs[0][bofs0] = cvt8(b4[0], b4[1]);  // compiler drains B(0) regs
  *(bf16x8*)&Bs[0][bofs1] = cvt8(b4[2], b4[3]);
  G2_LOADB(32);                                  // 4 vm (B(1))
  asm volatile("s_waitcnt vmcnt(4) lgkmcnt(0)" ::: "memory");  // A(0) done
  __builtin_amdgcn_sched_barrier(0);
  __builtin_amdgcn_s_barrier();
  __builtin_amdgcn_sched_barrier(0);

#define G2_STEP_FULL(CUR)                                                     \
  { G2_STAGE(k0 + 32, (CUR)^1);                                               \
    G2_LOADB(k0 + 64);                                                        \
    __builtin_amdgcn_sched_barrier(0);                                        \
    G2_MFMA(CUR);                                                             \
    asm volatile("s_waitcnt vmcnt(4) lgkmcnt(0)" ::: "memory");               \
    __builtin_amdgcn_sched_barrier(0);                                        \
    __builtin_amdgcn_s_barrier();                                             \
    __builtin_amdgcn_sched_barrier(0);                                        \
    k0 += 32; }

  int k0 = 0;
  while (k0 < FDIM/4 - 64) {      // t = 0..13: always another B(k0+64) to load
    G2_STEP_FULL(0);
    G2_STEP_FULL(1);
  }
  // k0 == 448: stage last tile (480 -> buf1), no more B loads
  G2_STAGE(480, 1);
  __builtin_amdgcn_sched_barrier(0);
  G2_MFMA(0);
  asm volatile("s_waitcnt vmcnt(0) lgkmcnt(0)" ::: "memory");
  __builtin_amdgcn_sched_barrier(0);
  __builtin_amdgcn_s_barrier();
  __builtin_amdgcn_sched_barrier(0);
  G2_MFMA(1);

#undef G2_STEP_FULL
#undef G2_MFMA
#undef G2_STAGE
#undef G2_LOADB

  // epilogue: + b2 (k-chunk 0 only), scale, atomic scatter-add
  #pragma unroll
  for (int i = 0; i < 4; i++) {
    #pragma unroll
    for (int r = 0; r < 4; r++) {
      const int m = wm*64 + i*16 + quad*4 + r;
      if (m0 + m < nt) {
        const int slot = off + m0 + m;
        const int t    = etok[slot];
        const float s  = escale[slot];
        #pragma unroll
        for (int j = 0; j < 4; j++) {
          const int n = n0 + wn*64 + j*16 + lr;
          float v = acc[i][j][r];
          if (kc == 0) v += b2[e*HDIM + n];
          atomicAdd(&out[(size_t)t*HDIM + n], s * v);
        }
      }
    }
  }
}

extern "C" void kernel_launch(void* const* d_in, const int* in_sizes, int n_in,
                              void* d_out, int out_size, void* d_ws, size_t ws_size,
                              hipStream_t stream) {
  const float* hidden = (const float*)d_in[0];
  const int*   sel    = (const int*)d_in[1];
  const float* scal   = (const float*)d_in[2];
  const float* w1     = (const float*)d_in[3];
  const float* b1     = (const float*)d_in[4];
  const float* w2     = (const float*)d_in[5];
  const float* b2     = (const float*)d_in[6];
  float* out = (float*)d_out;

  char* ws = (char*)d_ws;
  int*    offsets = (int*)(ws + WB_OFFSETS);
  int*    etok    = (int*)(ws + WB_ETOK);
  float*  escale  = (float*)(ws + WB_ESCALE);
  bf16_t* act     = (bf16_t*)(ws + WB_ACT);
  bf16_t* hbf     = (bf16_t*)(ws + WB_H);

  hipMemsetAsync(d_out, 0, (size_t)out_size * sizeof(float), stream);

  route_all<<<1, 256, 0, stream>>>(sel, scal, offsets, etok, escale);
  convert_h<<<(int)(H_ELEMS/8/256), 256, 0, stream>>>(hidden, hbf);

  // gemm1: x = n-tile (32), y = m-tile (16; ~2 live per expert), z = expert.
  gemm1_v6<<<dim3(FDIM/64, NENT/128, NEXP), 256, 0, stream>>>(hbf, w1, b1, offsets, etok, act);
  // gemm2: x = n-tile(8) x splitK(4), y = m-tile, z = expert. 512 live blocks.
  gemm2_v6<<<dim3((HDIM/128)*4, NENT/128, NEXP), 256, 0, stream>>>(act, w2, b2, offsets, etok, escale, out);
}

// Round 2
// 330.141 us; speedup vs baseline: 1.0356x; 1.0356x over previous
//
#include <hip/hip_runtime.h>
#include <hip/hip_bf16.h>
#include <cstdint>
#include <cstddef>

// Problem constants (fixed by the reference)
#define TDIM 1024
#define HDIM 1024
#define FDIM 2048
#define NEXP 8
#define NENT 2048   // T * K

typedef __bf16 bf16_t;
typedef __bf16 bf16x4 __attribute__((ext_vector_type(4)));
typedef __bf16 bf16x8 __attribute__((ext_vector_type(8)));
typedef float  f32x4  __attribute__((ext_vector_type(4)));

#define H_ELEMS ((size_t)TDIM*HDIM)   // 1048576

// ---------------- workspace layout (bytes) ----------------
#define WB_OFFSETS 0                                   // int[16]
#define WB_ETOK    64
#define WB_ESCALE  (WB_ETOK + NENT*4)
#define WB_ACT     16512                               // bf16[NENT][FDIM] = 8 MB
#define WB_H       (WB_ACT + (size_t)NENT*FDIM*2)      // bf16[T][H] = 2 MB

__device__ __forceinline__ void gload16(const void* g, void* l) {
  __builtin_amdgcn_global_load_lds((const __attribute__((address_space(1))) void*)g,
                                   (__attribute__((address_space(3))) void*)l, 16, 0, 0);
}

__device__ __forceinline__ bf16x8 cvt8(const float4 a, const float4 b) {
  bf16x8 o;
  o[0]=(bf16_t)a.x; o[1]=(bf16_t)a.y; o[2]=(bf16_t)a.z; o[3]=(bf16_t)a.w;
  o[4]=(bf16_t)b.x; o[5]=(bf16_t)b.y; o[6]=(bf16_t)b.z; o[7]=(bf16_t)b.w;
  return o;
}

// 3-bit bank swizzle: seg position = seg ^ (row&3) ^ ((row>>2)&3).
__device__ __forceinline__ int segswz(int seg, int row) {
  return seg ^ (row & 3) ^ ((row >> 2) & 3);
}

// ---------------- routing (single block, one launch) ----------------
__global__ void route_all(const int* __restrict__ sel, const float* __restrict__ scal,
                          int* __restrict__ offsets, int* __restrict__ etok,
                          float* __restrict__ escale) {
  __shared__ int cnt[NEXP], cnt2[NEXP], offs[NEXP+1];
  const int t = threadIdx.x;    // 256 threads, 8 entries each
  if (t < NEXP) { cnt[t] = 0; cnt2[t] = 0; }
  __syncthreads();
  int e8[8];
  #pragma unroll
  for (int q = 0; q < 8; q++) {
    int i = t*8 + q;
    e8[q] = sel[i];
    atomicAdd(&cnt[e8[q]], 1);
  }
  __syncthreads();
  if (t == 0) {
    int s = 0;
    for (int e = 0; e < NEXP; e++) { offs[e] = s; offsets[e] = s; s += cnt[e]; }
    offs[NEXP] = s; offsets[NEXP] = s;
  }
  __syncthreads();
  #pragma unroll
  for (int q = 0; q < 8; q++) {
    int i = t*8 + q;
    int e = e8[q];
    int pos = offs[e] + atomicAdd(&cnt2[e], 1);
    etok[pos]   = i >> 1;       // TOPK == 2
    escale[pos] = scal[i];
  }
}

// ---------------- hidden fp32 -> bf16 ----------------
__global__ void convert_h(const float* __restrict__ h, bf16_t* __restrict__ hbf) {
  size_t idx = ((size_t)blockIdx.x*256 + threadIdx.x) * 8;
  float4 v0 = ((const float4*)(h + idx))[0];
  float4 v1 = ((const float4*)(h + idx))[1];
  *(bf16x8*)(hbf + idx) = cvt8(v0, v1);
}

// ======== pipelined grouped GEMMs ========
// GRID FIX (v7): live blocks must have CONSECUTIVE linear ids.
// Old grid (n, m-tile, expert) put m-tile in y: live ids = x + 32y + 512z,
// whose within-XCD CU slot (id/8 mod 32) = (x>>3) + 4y ∈ {0..7} for ALL live
// blocks -> 512 live blocks piled onto 64 of 256 CUs (MfmaUtil 9.4% ≈ 37%/4).
// New grid: x = n-tile, y = expert, z = m-tile (slowest). Live ids 0..511
// contiguous -> uniform across all 8 XCDs x 32 CUs.

// GEMM1: act = silu(x@w1g^T + b1g) * (x@w1l^T + b1l)
__global__ __launch_bounds__(256, 3) void gemm1_v7(
    const bf16_t* __restrict__ hbf, const float* __restrict__ w1,
    const float* __restrict__ b1, const int* __restrict__ offsets,
    const int* __restrict__ etok, bf16_t* __restrict__ act)
{
  const int e   = blockIdx.y;
  const int off = offsets[e];
  const int nt  = offsets[e+1] - off;
  const int m0  = blockIdx.z * 128;
  if (m0 >= nt) return;
  const int n0  = blockIdx.x * 64;

  __shared__ __align__(16) bf16_t As[2][128*32];
  __shared__ __align__(16) bf16_t Bg[2][64*32];
  __shared__ __align__(16) bf16_t Bl[2][64*32];

  const int tid  = threadIdx.x;
  const int w    = tid >> 6, lane = tid & 63;
  const int quad = lane >> 4, lr = lane & 15;
  const int wm   = w >> 1,  wn = w & 1;

  // ---- A staging: wave w, inst i covers LDS rows [i*64 + w*16, +16) ----
  const bf16_t* asrc0; const bf16_t* asrc1;
  int arow0, arow1;
  {
    const int r0 = 0*64 + w*16 + (lane >> 2);
    const int r1 = 1*64 + w*16 + (lane >> 2);
    const int s0 = segswz(lane & 3, r0);
    const int s1 = segswz(lane & 3, r1);
    int e0 = m0 + r0; if (e0 > nt-1) e0 = nt-1;   // clamp; masked in epilogue
    int e1 = m0 + r1; if (e1 > nt-1) e1 = nt-1;
    asrc0 = hbf + (size_t)etok[off + e0]*HDIM + s0*8;
    asrc1 = hbf + (size_t)etok[off + e1]*HDIM + s1*8;
    arow0 = (0*64 + w*16)*32;                     // + lane*16B implicit
    arow1 = (1*64 + w*16)*32;
  }

  // ---- B staging: thread t -> row t>>2 (0..63), seg t&3 ----
  const int br = tid >> 2, bs = tid & 3;
  const float* gsrc = w1 + ((size_t)e*2*FDIM + (size_t)(n0 + br))*HDIM + bs*8;
  const float* lsrc = gsrc + (size_t)FDIM*HDIM;
  const int bofs = br*32 + (segswz(bs, br) << 3);

  // ---- loop-invariant fragment LDS offsets ----
  int aoff[4], boff[2];
  #pragma unroll
  for (int i = 0; i < 4; i++) {
    const int r = wm*64 + i*16 + lr;
    aoff[i] = r*32 + (segswz(quad, r) << 3);
  }
  #pragma unroll
  for (int j = 0; j < 2; j++) {
    const int r = wn*32 + j*16 + lr;
    boff[j] = r*32 + (segswz(quad, r) << 3);
  }

  f32x4 accg[4][2] = {}, accl[4][2] = {};
  float4 g4[2], l4[2];

#define G1_LOADB(K0)                                                          \
  { const float4* p_ = (const float4*)(gsrc + (K0)); g4[0]=p_[0]; g4[1]=p_[1];\
    const float4* q_ = (const float4*)(lsrc + (K0)); l4[0]=q_[0]; l4[1]=q_[1]; }

#define G1_STAGE(K0, NXT)                                                     \
  { *(bf16x8*)&Bg[NXT][bofs] = cvt8(g4[0], g4[1]);                            \
    *(bf16x8*)&Bl[NXT][bofs] = cvt8(l4[0], l4[1]);                            \
    __builtin_amdgcn_sched_barrier(0);                                        \
    gload16(asrc0 + (K0), &As[NXT][arow0]);                                   \
    gload16(asrc1 + (K0), &As[NXT][arow1]);                                   \
    __builtin_amdgcn_sched_barrier(0); }

#define G1_MFMA(CUR)                                                          \
  { bf16x8 af[4], gf[2], lf[2];                                               \
    _Pragma("unroll")                                                         \
    for (int i = 0; i < 4; i++) af[i] = *(const bf16x8*)&As[CUR][aoff[i]];    \
    _Pragma("unroll")                                                         \
    for (int j = 0; j < 2; j++) {                                             \
      gf[j] = *(const bf16x8*)&Bg[CUR][boff[j]];                              \
      lf[j] = *(const bf16x8*)&Bl[CUR][boff[j]];                              \
    }                                                                         \
    _Pragma("unroll")                                                         \
    for (int i = 0; i < 4; i++)                                               \
      _Pragma("unroll")                                                       \
      for (int j = 0; j < 2; j++) {                                           \
        accg[i][j] = __builtin_amdgcn_mfma_f32_16x16x32_bf16(af[i], gf[j], accg[i][j], 0, 0, 0); \
        accl[i][j] = __builtin_amdgcn_mfma_f32_16x16x32_bf16(af[i], lf[j], accl[i][j], 0, 0, 0); \
      } }

  // ---- prologue: stage tile 0 into buf0, prefetch B(1) ----
  G1_LOADB(0);                                   // 4 vm
  __builtin_amdgcn_sched_barrier(0);
  gload16(asrc0 + 0, &As[0][arow0]);             // 2 vm
  gload16(asrc1 + 0, &As[0][arow1]);
  __builtin_amdgcn_sched_barrier(0);
  *(bf16x8*)&Bg[0][bofs] = cvt8(g4[0], g4[1]);   // compiler drains B(0) regs
  *(bf16x8*)&Bl[0][bofs] = cvt8(l4[0], l4[1]);
  G1_LOADB(32);                                  // 4 vm (B(1))
  asm volatile("s_waitcnt vmcnt(4) lgkmcnt(0)" ::: "memory");  // A(0) done
  __builtin_amdgcn_sched_barrier(0);
  __builtin_amdgcn_s_barrier();
  __builtin_amdgcn_sched_barrier(0);

#define G1_STEP_FULL(CUR)                                                     \
  { G1_STAGE(k0 + 32, (CUR)^1);                                               \
    G1_LOADB(k0 + 64);                                                        \
    __builtin_amdgcn_sched_barrier(0);                                        \
    G1_MFMA(CUR);                                                             \
    asm volatile("s_waitcnt vmcnt(4) lgkmcnt(0)" ::: "memory");               \
    __builtin_amdgcn_sched_barrier(0);                                        \
    __builtin_amdgcn_s_barrier();                                             \
    __builtin_amdgcn_sched_barrier(0);                                        \
    k0 += 32; }

  int k0 = 0;
  while (k0 < HDIM - 64) {        // t = 0..29: always another B(k0+64) to load
    G1_STEP_FULL(0);
    G1_STEP_FULL(1);
  }
  // k0 == 960: stage last tile (992 -> buf1), no more B loads
  G1_STAGE(992, 1);
  __builtin_amdgcn_sched_barrier(0);
  G1_MFMA(0);
  asm volatile("s_waitcnt vmcnt(0) lgkmcnt(0)" ::: "memory");
  __builtin_amdgcn_sched_barrier(0);
  __builtin_amdgcn_s_barrier();
  __builtin_amdgcn_sched_barrier(0);
  G1_MFMA(1);

#undef G1_STEP_FULL
#undef G1_MFMA
#undef G1_STAGE
#undef G1_LOADB

  // epilogue: bias + silu(gate)*lin -> act (bf16)
  #pragma unroll
  for (int j = 0; j < 2; j++) {
    const int f = n0 + wn*32 + j*16 + lr;
    const float bg_ = b1[e*2*FDIM + f];
    const float bl_ = b1[e*2*FDIM + FDIM + f];
    #pragma unroll
    for (int i = 0; i < 4; i++) {
      #pragma unroll
      for (int r = 0; r < 4; r++) {
        const int m = wm*64 + i*16 + quad*4 + r;
        if (m0 + m < nt) {
          const float g = accg[i][j][r] + bg_;
          const float l = accl[i][j][r] + bl_;
          const float s = g / (1.f + __expf(-g)) * l;
          act[(size_t)(off + m0 + m)*FDIM + f] = (bf16_t)s;
        }
      }
    }
  }
}

// GEMM2: y = act @ w2^T + b2; out[token] += scale * y  (atomic, split-K x4)
__global__ __launch_bounds__(256, 3) void gemm2_v7(
    const bf16_t* __restrict__ act, const float* __restrict__ w2,
    const float* __restrict__ b2, const int* __restrict__ offsets,
    const int* __restrict__ etok, const float* __restrict__ escale,
    float* __restrict__ out)
{
  const int e   = blockIdx.y;
  const int off = offsets[e];
  const int nt  = offsets[e+1] - off;
  const int m0  = blockIdx.z * 128;
  if (m0 >= nt) return;
  const int n0  = (blockIdx.x >> 2) * 128;
  const int kc  = blockIdx.x & 3;
  const int kbeg = kc * (FDIM/4);          // 512-chunk, 16 iters

  __shared__ __align__(16) bf16_t As[2][128*32];
  __shared__ __align__(16) bf16_t Bs[2][128*32];

  const int tid  = threadIdx.x;
  const int w    = tid >> 6, lane = tid & 63;
  const int quad = lane >> 4, lr = lane & 15;
  const int wm   = w >> 1,  wn = w & 1;

  const bf16_t* asrc0; const bf16_t* asrc1;
  int arow0, arow1;
  {
    const int r0 = 0*64 + w*16 + (lane >> 2);
    const int r1 = 1*64 + w*16 + (lane >> 2);
    const int s0 = segswz(lane & 3, r0);
    const int s1 = segswz(lane & 3, r1);
    int e0 = m0 + r0; if (e0 > nt-1) e0 = nt-1;
    int e1 = m0 + r1; if (e1 > nt-1) e1 = nt-1;
    asrc0 = act + (size_t)(off + e0)*FDIM + kbeg + s0*8;
    asrc1 = act + (size_t)(off + e1)*FDIM + kbeg + s1*8;
    arow0 = (0*64 + w*16)*32;
    arow1 = (1*64 + w*16)*32;
  }

  // B staging: thread t -> row t>>1 (0..127), col-half t&1 (segs 2c, 2c+1)
  const int br = tid >> 1, bc = tid & 1;
  const float* bsrc = w2 + ((size_t)e*HDIM + (size_t)(n0 + br))*FDIM + kbeg + bc*16;
  const int bofs0 = br*32 + (segswz(2*bc,   br) << 3);
  const int bofs1 = br*32 + (segswz(2*bc+1, br) << 3);

  int aoff[4], boff[4];
  #pragma unroll
  for (int i = 0; i < 4; i++) {
    const int r = wm*64 + i*16 + lr;
    aoff[i] = r*32 + (segswz(quad, r) << 3);
  }
  #pragma unroll
  for (int j = 0; j < 4; j++) {
    const int r = wn*64 + j*16 + lr;
    boff[j] = r*32 + (segswz(quad, r) << 3);
  }

  f32x4 acc[4][4] = {};
  float4 b4[4];

#define G2_LOADB(K0)                                                          \
  { const float4* p_ = (const float4*)(bsrc + (K0));                          \
    b4[0]=p_[0]; b4[1]=p_[1]; b4[2]=p_[2]; b4[3]=p_[3]; }

#define G2_STAGE(K0, NXT)                                                     \
  { *(bf16x8*)&Bs[NXT][bofs0] = cvt8(b4[0], b4[1]);                           \
    *(bf16x8*)&Bs[NXT][bofs1] = cvt8(b4[2], b4[3]);                           \
    __builtin_amdgcn_sched_barrier(0);                                        \
    gload16(asrc0 + (K0), &As[NXT][arow0]);                                   \
    gload16(asrc1 + (K0), &As[NXT][arow1]);                                   \
    __builtin_amdgcn_sched_barrier(0); }

#define G2_MFMA(CUR)                                                          \
  { bf16x8 af[4], bfr[4];                                                     \
    _Pragma("unroll")                                                         \
    for (int i = 0; i < 4; i++) af[i] = *(const bf16x8*)&As[CUR][aoff[i]];    \
    _Pragma("unroll")                                                         \
    for (int j = 0; j < 4; j++) bfr[j] = *(const bf16x8*)&Bs[CUR][boff[j]];   \
    _Pragma("unroll")                                                         \
    for (int i = 0; i < 4; i++)                                               \
      _Pragma("unroll")                                                       \
      for (int j = 0; j < 4; j++)                                             \
        acc[i][j] = __builtin_amdgcn_mfma_f32_16x16x32_bf16(af[i], bfr[j], acc[i][j], 0, 0, 0); }

  // ---- prologue ----
  G2_LOADB(0);                                   // 4 vm
  __builtin_amdgcn_sched_barrier(0);
  gload16(asrc0 + 0, &As[0][arow0]);             // 2 vm
  gload16(asrc1 + 0, &As[0][arow1]);
  __builtin_amdgcn_sched_barrier(0);
  *(bf16x8*)&Bs[0][bofs0] = cvt8(b4[0], b4[1]);  // compiler drains B(0) regs
  *(bf16x8*)&Bs[0][bofs1] = cvt8(b4[2], b4[3]);
  G2_LOADB(32);                                  // 4 vm (B(1))
  asm volatile("s_waitcnt vmcnt(4) lgkmcnt(0)" ::: "memory");  // A(0) done
  __builtin_amdgcn_sched_barrier(0);
  __builtin_amdgcn_s_barrier();
  __builtin_amdgcn_sched_barrier(0);

#define G2_STEP_FULL(CUR)                                                     \
  { G2_STAGE(k0 + 32, (CUR)^1);                                               \
    G2_LOADB(k0 + 64);                                                        \
    __builtin_amdgcn_sched_barrier(0);                                        \
    G2_MFMA(CUR);                                                             \
    asm volatile("s_waitcnt vmcnt(4) lgkmcnt(0)" ::: "memory");               \
    __builtin_amdgcn_sched_barrier(0);                                        \
    __builtin_amdgcn_s_barrier();                                             \
    __builtin_amdgcn_sched_barrier(0);                                        \
    k0 += 32; }

  int k0 = 0;
  while (k0 < FDIM/4 - 64) {      // t = 0..13: always another B(k0+64) to load
    G2_STEP_FULL(0);
    G2_STEP_FULL(1);
  }
  // k0 == 448: stage last tile (480 -> buf1), no more B loads
  G2_STAGE(480, 1);
  __builtin_amdgcn_sched_barrier(0);
  G2_MFMA(0);
  asm volatile("s_waitcnt vmcnt(0) lgkmcnt(0)" ::: "memory");
  __builtin_amdgcn_sched_barrier(0);
  __builtin_amdgcn_s_barrier();
  __builtin_amdgcn_sched_barrier(0);
  G2_MFMA(1);

#undef G2_STEP_FULL
#undef G2_MFMA
#undef G2_STAGE
#undef G2_LOADB

  // epilogue: + b2 (k-chunk 0 only), scale, atomic scatter-add
  #pragma unroll
  for (int i = 0; i < 4; i++) {
    #pragma unroll
    for (int r = 0; r < 4; r++) {
      const int m = wm*64 + i*16 + quad*4 + r;
      if (m0 + m < nt) {
        const int slot = off + m0 + m;
        const int t    = etok[slot];
        const float s  = escale[slot];
        #pragma unroll
        for (int j = 0; j < 4; j++) {
          const int n = n0 + wn*64 + j*16 + lr;
          float v = acc[i][j][r];
          if (kc == 0) v += b2[e*HDIM + n];
          atomicAdd(&out[(size_t)t*HDIM + n], s * v);
        }
      }
    }
  }
}

extern "C" void kernel_launch(void* const* d_in, const int* in_sizes, int n_in,
                              void* d_out, int out_size, void* d_ws, size_t ws_size,
                              hipStream_t stream) {
  const float* hidden = (const float*)d_in[0];
  const int*   sel    = (const int*)d_in[1];
  const float* scal   = (const float*)d_in[2];
  const float* w1     = (const float*)d_in[3];
  const float* b1     = (const float*)d_in[4];
  const float* w2     = (const float*)d_in[5];
  const float* b2     = (const float*)d_in[6];
  float* out = (float*)d_out;

  char* ws = (char*)d_ws;
  int*    offsets = (int*)(ws + WB_OFFSETS);
  int*    etok    = (int*)(ws + WB_ETOK);
  float*  escale  = (float*)(ws + WB_ESCALE);
  bf16_t* act     = (bf16_t*)(ws + WB_ACT);
  bf16_t* hbf     = (bf16_t*)(ws + WB_H);

  hipMemsetAsync(d_out, 0, (size_t)out_size * sizeof(float), stream);

  route_all<<<1, 256, 0, stream>>>(sel, scal, offsets, etok, escale);
  convert_h<<<(int)(H_ELEMS/8/256), 256, 0, stream>>>(hidden, hbf);

  // gemm1: x = n-tile (32), y = expert (8), z = m-tile (16, mostly dead past 2).
  // Live blocks get consecutive linear ids -> spread over all XCDs/CUs.
  gemm1_v7<<<dim3(FDIM/64, NEXP, NENT/128), 256, 0, stream>>>(hbf, w1, b1, offsets, etok, act);
  // gemm2: x = n-tile(8) x splitK(4), y = expert, z = m-tile.
  gemm2_v7<<<dim3((HDIM/128)*4, NEXP, NENT/128), 256, 0, stream>>>(act, w2, b2, offsets, etok, escale, out);
}

// Round 3
// 328.471 us; speedup vs baseline: 1.0409x; 1.0051x over previous
//
#include <hip/hip_runtime.h>
#include <hip/hip_bf16.h>
#include <cstdint>
#include <cstddef>

// Problem constants (fixed by the reference)
#define TDIM 1024
#define HDIM 1024
#define FDIM 2048
#define NEXP 8
#define NENT 2048   // T * K

typedef __bf16 bf16_t;
typedef __bf16 bf16x4 __attribute__((ext_vector_type(4)));
typedef __bf16 bf16x8 __attribute__((ext_vector_type(8)));
typedef float  f32x4  __attribute__((ext_vector_type(4)));

#define H_ELEMS ((size_t)TDIM*HDIM)   // 1048576

// ---------------- workspace layout (bytes) ----------------
#define WB_OFFSETS 0                                   // int[16]
#define WB_ETOK    64
#define WB_ESCALE  (WB_ETOK + NENT*4)
#define WB_ACT     16512                               // bf16[NENT][FDIM] = 8 MB
#define WB_H       (WB_ACT + (size_t)NENT*FDIM*2)      // bf16[T][H] = 2 MB

__device__ __forceinline__ void gload16(const void* g, void* l) {
  __builtin_amdgcn_global_load_lds((const __attribute__((address_space(1))) void*)g,
                                   (__attribute__((address_space(3))) void*)l, 16, 0, 0);
}

__device__ __forceinline__ bf16x8 cvt8(const float4 a, const float4 b) {
  bf16x8 o;
  o[0]=(bf16_t)a.x; o[1]=(bf16_t)a.y; o[2]=(bf16_t)a.z; o[3]=(bf16_t)a.w;
  o[4]=(bf16_t)b.x; o[5]=(bf16_t)b.y; o[6]=(bf16_t)b.z; o[7]=(bf16_t)b.w;
  return o;
}

// 3-bit bank swizzle: seg position = seg ^ (row&3) ^ ((row>>2)&3).
__device__ __forceinline__ int segswz(int seg, int row) {
  return seg ^ (row & 3) ^ ((row >> 2) & 3);
}

// ---------------- routing (single block, one launch) ----------------
__global__ void route_all(const int* __restrict__ sel, const float* __restrict__ scal,
                          int* __restrict__ offsets, int* __restrict__ etok,
                          float* __restrict__ escale) {
  __shared__ int cnt[NEXP], cnt2[NEXP], offs[NEXP+1];
  const int t = threadIdx.x;    // 256 threads, 8 entries each
  if (t < NEXP) { cnt[t] = 0; cnt2[t] = 0; }
  __syncthreads();
  int e8[8];
  #pragma unroll
  for (int q = 0; q < 8; q++) {
    int i = t*8 + q;
    e8[q] = sel[i];
    atomicAdd(&cnt[e8[q]], 1);
  }
  __syncthreads();
  if (t == 0) {
    int s = 0;
    for (int e = 0; e < NEXP; e++) { offs[e] = s; offsets[e] = s; s += cnt[e]; }
    offs[NEXP] = s; offsets[NEXP] = s;
  }
  __syncthreads();
  #pragma unroll
  for (int q = 0; q < 8; q++) {
    int i = t*8 + q;
    int e = e8[q];
    int pos = offs[e] + atomicAdd(&cnt2[e], 1);
    etok[pos]   = i >> 1;       // TOPK == 2
    escale[pos] = scal[i];
  }
}

// ---------------- hidden fp32 -> bf16 ----------------
__global__ void convert_h(const float* __restrict__ h, bf16_t* __restrict__ hbf) {
  size_t idx = ((size_t)blockIdx.x*256 + threadIdx.x) * 8;
  float4 v0 = ((const float4*)(h + idx))[0];
  float4 v1 = ((const float4*)(h + idx))[1];
  *(bf16x8*)(hbf + idx) = cvt8(v0, v1);
}

// ======== pipelined grouped GEMMs — v8: DEPTH-2 B-register prefetch ========
// v6/v7 exposed the w1/w2 fp32 load latency (~600-900 cyc, L3/HBM) at the
// ds_write that opens every iteration: B(t+1) was loaded only ~400 cyc
// earlier (during iter t's MFMA phase), so the compiler's vmcnt wait before
// the ds_write stalled the wave BEFORE the A-loads/MFMA of iter t+1 issued.
// Fix: two B register sets ping-pong. Iter t writes B(t+1) (loaded at t-2,
// ~2 full iterations of slack) and issues B(t+3). Steady-state wait is
// vmcnt(4): drains A(t+1) + stale B(t+2), leaves B(t+3)'s 4 loads in flight.

// GEMM1: act = silu(x@w1g^T + b1g) * (x@w1l^T + b1l)
__global__ __launch_bounds__(256, 3) void gemm1_v8(
    const bf16_t* __restrict__ hbf, const float* __restrict__ w1,
    const float* __restrict__ b1, const int* __restrict__ offsets,
    const int* __restrict__ etok, bf16_t* __restrict__ act)
{
  const int e   = blockIdx.y;
  const int off = offsets[e];
  const int nt  = offsets[e+1] - off;
  const int m0  = blockIdx.z * 128;
  if (m0 >= nt) return;
  const int n0  = blockIdx.x * 64;

  __shared__ __align__(16) bf16_t As[2][128*32];
  __shared__ __align__(16) bf16_t Bg[2][64*32];
  __shared__ __align__(16) bf16_t Bl[2][64*32];

  const int tid  = threadIdx.x;
  const int w    = tid >> 6, lane = tid & 63;
  const int quad = lane >> 4, lr = lane & 15;
  const int wm   = w >> 1,  wn = w & 1;

  // ---- A staging: wave w, inst i covers LDS rows [i*64 + w*16, +16) ----
  const bf16_t* asrc0; const bf16_t* asrc1;
  int arow0, arow1;
  {
    const int r0 = 0*64 + w*16 + (lane >> 2);
    const int r1 = 1*64 + w*16 + (lane >> 2);
    const int s0 = segswz(lane & 3, r0);
    const int s1 = segswz(lane & 3, r1);
    int e0 = m0 + r0; if (e0 > nt-1) e0 = nt-1;   // clamp; masked in epilogue
    int e1 = m0 + r1; if (e1 > nt-1) e1 = nt-1;
    asrc0 = hbf + (size_t)etok[off + e0]*HDIM + s0*8;
    asrc1 = hbf + (size_t)etok[off + e1]*HDIM + s1*8;
    arow0 = (0*64 + w*16)*32;                     // + lane*16B implicit
    arow1 = (1*64 + w*16)*32;
  }

  // ---- B staging: thread t -> row t>>2 (0..63), seg t&3 ----
  const int br = tid >> 2, bs = tid & 3;
  const float* gsrc = w1 + ((size_t)e*2*FDIM + (size_t)(n0 + br))*HDIM + bs*8;
  const float* lsrc = gsrc + (size_t)FDIM*HDIM;
  const int bofs = br*32 + (segswz(bs, br) << 3);

  // ---- loop-invariant fragment LDS offsets ----
  int aoff[4], boff[2];
  #pragma unroll
  for (int i = 0; i < 4; i++) {
    const int r = wm*64 + i*16 + lr;
    aoff[i] = r*32 + (segswz(quad, r) << 3);
  }
  #pragma unroll
  for (int j = 0; j < 2; j++) {
    const int r = wn*32 + j*16 + lr;
    boff[j] = r*32 + (segswz(quad, r) << 3);
  }

  f32x4 accg[4][2] = {}, accl[4][2] = {};
  float4 g4[2][2], l4[2][2];     // two ping-pong B register sets (depth-2)

#define G1_LOADB(SET, K0)                                                     \
  { const float4* p_ = (const float4*)(gsrc + (K0));                          \
    g4[SET][0]=p_[0]; g4[SET][1]=p_[1];                                       \
    const float4* q_ = (const float4*)(lsrc + (K0));                          \
    l4[SET][0]=q_[0]; l4[SET][1]=q_[1]; }

#define G1_WRITEB(NXT, SET)                                                   \
  { *(bf16x8*)&Bg[NXT][bofs] = cvt8(g4[SET][0], g4[SET][1]);                  \
    *(bf16x8*)&Bl[NXT][bofs] = cvt8(l4[SET][0], l4[SET][1]); }

#define G1_MFMA(CUR)                                                          \
  { bf16x8 af[4], gf[2], lf[2];                                               \
    _Pragma("unroll")                                                         \
    for (int i = 0; i < 4; i++) af[i] = *(const bf16x8*)&As[CUR][aoff[i]];    \
    _Pragma("unroll")                                                         \
    for (int j = 0; j < 2; j++) {                                             \
      gf[j] = *(const bf16x8*)&Bg[CUR][boff[j]];                              \
      lf[j] = *(const bf16x8*)&Bl[CUR][boff[j]];                              \
    }                                                                         \
    _Pragma("unroll")                                                         \
    for (int i = 0; i < 4; i++)                                               \
      _Pragma("unroll")                                                       \
      for (int j = 0; j < 2; j++) {                                           \
        accg[i][j] = __builtin_amdgcn_mfma_f32_16x16x32_bf16(af[i], gf[j], accg[i][j], 0, 0, 0); \
        accl[i][j] = __builtin_amdgcn_mfma_f32_16x16x32_bf16(af[i], lf[j], accl[i][j], 0, 0, 0); \
      } }

  // ---- prologue: tile0 -> buf0; B(1)->set0, B(2)->set1 in flight ----
  G1_LOADB(0, 0);                                // B(0) -> set0, 4 vm
  __builtin_amdgcn_sched_barrier(0);
  gload16(asrc0 + 0, &As[0][arow0]);             // A(0), 2 vm
  gload16(asrc1 + 0, &As[0][arow1]);
  __builtin_amdgcn_sched_barrier(0);
  G1_WRITEB(0, 0);                               // compiler drains B(0) regs
  G1_LOADB(0, 32);                               // B(1) -> set0, 4 vm
  G1_LOADB(1, 64);                               // B(2) -> set1, 4 vm
  asm volatile("s_waitcnt vmcnt(8) lgkmcnt(0)" ::: "memory");  // A(0) done
  __builtin_amdgcn_sched_barrier(0);
  __builtin_amdgcn_s_barrier();
  __builtin_amdgcn_sched_barrier(0);

  // steady step at tile t (k0 = t*32): write B(t+1) from SET (loaded t-2),
  // stage A(t+1), issue B(t+3) -> SET, compute tile t.
#define G1_STEP(CUR, SET)                                                     \
  { G1_WRITEB((CUR)^1, SET);                                                  \
    __builtin_amdgcn_sched_barrier(0);                                        \
    gload16(asrc0 + k0 + 32, &As[(CUR)^1][arow0]);                            \
    gload16(asrc1 + k0 + 32, &As[(CUR)^1][arow1]);                            \
    __builtin_amdgcn_sched_barrier(0);                                        \
    G1_LOADB(SET, k0 + 96);                                                   \
    __builtin_amdgcn_sched_barrier(0);                                        \
    G1_MFMA(CUR);                                                             \
    asm volatile("s_waitcnt vmcnt(4) lgkmcnt(0)" ::: "memory");               \
    __builtin_amdgcn_sched_barrier(0);                                        \
    __builtin_amdgcn_s_barrier();                                             \
    __builtin_amdgcn_sched_barrier(0);                                        \
    k0 += 32; }

  int k0 = 0;
  while (k0 < 896) {              // t = 0..27 (pairs)
    G1_STEP(0, 0);
    G1_STEP(1, 1);
  }
  G1_STEP(0, 0);                  // t = 28: loads B(31) at k0+96 = 992
  // t = 29 (k0 = 928, CUR = 1): write B(30) from set1, stage A(30), no B-load
  G1_WRITEB(0, 1);
  __builtin_amdgcn_sched_barrier(0);
  gload16(asrc0 + 960, &As[0][arow0]);
  gload16(asrc1 + 960, &As[0][arow1]);
  __builtin_amdgcn_sched_barrier(0);
  G1_MFMA(1);
  asm volatile("s_waitcnt vmcnt(0) lgkmcnt(0)" ::: "memory");
  __builtin_amdgcn_sched_barrier(0);
  __builtin_amdgcn_s_barrier();
  __builtin_amdgcn_sched_barrier(0);
  // t = 30 (CUR = 0): write B(31) from set0, stage A(31)
  G1_WRITEB(1, 0);
  __builtin_amdgcn_sched_barrier(0);
  gload16(asrc0 + 992, &As[1][arow0]);
  gload16(asrc1 + 992, &As[1][arow1]);
  __builtin_amdgcn_sched_barrier(0);
  G1_MFMA(0);
  asm volatile("s_waitcnt vmcnt(0) lgkmcnt(0)" ::: "memory");
  __builtin_amdgcn_sched_barrier(0);
  __builtin_amdgcn_s_barrier();
  __builtin_amdgcn_sched_barrier(0);
  // t = 31
  G1_MFMA(1);

#undef G1_STEP
#undef G1_MFMA
#undef G1_WRITEB
#undef G1_LOADB

  // epilogue: bias + silu(gate)*lin -> act (bf16)
  #pragma unroll
  for (int j = 0; j < 2; j++) {
    const int f = n0 + wn*32 + j*16 + lr;
    const float bg_ = b1[e*2*FDIM + f];
    const float bl_ = b1[e*2*FDIM + FDIM + f];
    #pragma unroll
    for (int i = 0; i < 4; i++) {
      #pragma unroll
      for (int r = 0; r < 4; r++) {
        const int m = wm*64 + i*16 + quad*4 + r;
        if (m0 + m < nt) {
          const float g = accg[i][j][r] + bg_;
          const float l = accl[i][j][r] + bl_;
          const float s = g / (1.f + __expf(-g)) * l;
          act[(size_t)(off + m0 + m)*FDIM + f] = (bf16_t)s;
        }
      }
    }
  }
}

// GEMM2: y = act @ w2^T + b2; out[token] += scale * y  (atomic, split-K x4)
__global__ __launch_bounds__(256, 3) void gemm2_v8(
    const bf16_t* __restrict__ act, const float* __restrict__ w2,
    const float* __restrict__ b2, const int* __restrict__ offsets,
    const int* __restrict__ etok, const float* __restrict__ escale,
    float* __restrict__ out)
{
  const int e   = blockIdx.y;
  const int off = offsets[e];
  const int nt  = offsets[e+1] - off;
  const int m0  = blockIdx.z * 128;
  if (m0 >= nt) return;
  const int n0  = (blockIdx.x >> 2) * 128;
  const int kc  = blockIdx.x & 3;
  const int kbeg = kc * (FDIM/4);          // 512-chunk, 16 iters

  __shared__ __align__(16) bf16_t As[2][128*32];
  __shared__ __align__(16) bf16_t Bs[2][128*32];

  const int tid  = threadIdx.x;
  const int w    = tid >> 6, lane = tid & 63;
  const int quad = lane >> 4, lr = lane & 15;
  const int wm   = w >> 1,  wn = w & 1;

  const bf16_t* asrc0; const bf16_t* asrc1;
  int arow0, arow1;
  {
    const int r0 = 0*64 + w*16 + (lane >> 2);
    const int r1 = 1*64 + w*16 + (lane >> 2);
    const int s0 = segswz(lane & 3, r0);
    const int s1 = segswz(lane & 3, r1);
    int e0 = m0 + r0; if (e0 > nt-1) e0 = nt-1;
    int e1 = m0 + r1; if (e1 > nt-1) e1 = nt-1;
    asrc0 = act + (size_t)(off + e0)*FDIM + kbeg + s0*8;
    asrc1 = act + (size_t)(off + e1)*FDIM + kbeg + s1*8;
    arow0 = (0*64 + w*16)*32;
    arow1 = (1*64 + w*16)*32;
  }

  // B staging: thread t -> row t>>1 (0..127), col-half t&1 (segs 2c, 2c+1)
  const int br = tid >> 1, bc = tid & 1;
  const float* bsrc = w2 + ((size_t)e*HDIM + (size_t)(n0 + br))*FDIM + kbeg + bc*16;
  const int bofs0 = br*32 + (segswz(2*bc,   br) << 3);
  const int bofs1 = br*32 + (segswz(2*bc+1, br) << 3);

  int aoff[4], boff[4];
  #pragma unroll
  for (int i = 0; i < 4; i++) {
    const int r = wm*64 + i*16 + lr;
    aoff[i] = r*32 + (segswz(quad, r) << 3);
  }
  #pragma unroll
  for (int j = 0; j < 4; j++) {
    const int r = wn*64 + j*16 + lr;
    boff[j] = r*32 + (segswz(quad, r) << 3);
  }

  f32x4 acc[4][4] = {};
  float4 b4[2][4];               // two ping-pong B register sets (depth-2)

#define G2_LOADB(SET, K0)                                                     \
  { const float4* p_ = (const float4*)(bsrc + (K0));                          \
    b4[SET][0]=p_[0]; b4[SET][1]=p_[1]; b4[SET][2]=p_[2]; b4[SET][3]=p_[3]; }

#define G2_WRITEB(NXT, SET)                                                   \
  { *(bf16x8*)&Bs[NXT][bofs0] = cvt8(b4[SET][0], b4[SET][1]);                 \
    *(bf16x8*)&Bs[NXT][bofs1] = cvt8(b4[SET][2], b4[SET][3]); }

#define G2_MFMA(CUR)                                                          \
  { bf16x8 af[4], bfr[4];                                                     \
    _Pragma("unroll")                                                         \
    for (int i = 0; i < 4; i++) af[i] = *(const bf16x8*)&As[CUR][aoff[i]];    \
    _Pragma("unroll")                                                         \
    for (int j = 0; j < 4; j++) bfr[j] = *(const bf16x8*)&Bs[CUR][boff[j]];   \
    _Pragma("unroll")                                                         \
    for (int i = 0; i < 4; i++)                                               \
      _Pragma("unroll")                                                       \
      for (int j = 0; j < 4; j++)                                             \
        acc[i][j] = __builtin_amdgcn_mfma_f32_16x16x32_bf16(af[i], bfr[j], acc[i][j], 0, 0, 0); }

  // ---- prologue ----
  G2_LOADB(0, 0);                                // B(0) -> set0, 4 vm
  __builtin_amdgcn_sched_barrier(0);
  gload16(asrc0 + 0, &As[0][arow0]);             // A(0), 2 vm
  gload16(asrc1 + 0, &As[0][arow1]);
  __builtin_amdgcn_sched_barrier(0);
  G2_WRITEB(0, 0);                               // compiler drains B(0) regs
  G2_LOADB(0, 32);                               // B(1) -> set0
  G2_LOADB(1, 64);                               // B(2) -> set1
  asm volatile("s_waitcnt vmcnt(8) lgkmcnt(0)" ::: "memory");  // A(0) done
  __builtin_amdgcn_sched_barrier(0);
  __builtin_amdgcn_s_barrier();
  __builtin_amdgcn_sched_barrier(0);

#define G2_STEP(CUR, SET)                                                     \
  { G2_WRITEB((CUR)^1, SET);                                                  \
    __builtin_amdgcn_sched_barrier(0);                                        \
    gload16(asrc0 + k0 + 32, &As[(CUR)^1][arow0]);                            \
    gload16(asrc1 + k0 + 32, &As[(CUR)^1][arow1]);                            \
    __builtin_amdgcn_sched_barrier(0);                                        \
    G2_LOADB(SET, k0 + 96);                                                   \
    __builtin_amdgcn_sched_barrier(0);                                        \
    G2_MFMA(CUR);                                                             \
    asm volatile("s_waitcnt vmcnt(4) lgkmcnt(0)" ::: "memory");               \
    __builtin_amdgcn_sched_barrier(0);                                        \
    __builtin_amdgcn_s_barrier();                                             \
    __builtin_amdgcn_sched_barrier(0);                                        \
    k0 += 32; }

  int k0 = 0;
  while (k0 < 384) {              // t = 0..11 (pairs)
    G2_STEP(0, 0);
    G2_STEP(1, 1);
  }
  G2_STEP(0, 0);                  // t = 12: loads B(15) at k0+96 = 480
  // t = 13 (k0 = 416, CUR = 1): write B(14) from set1, stage A(14)
  G2_WRITEB(0, 1);
  __builtin_amdgcn_sched_barrier(0);
  gload16(asrc0 + 448, &As[0][arow0]);
  gload16(asrc1 + 448, &As[0][arow1]);
  __builtin_amdgcn_sched_barrier(0);
  G2_MFMA(1);
  asm volatile("s_waitcnt vmcnt(0) lgkmcnt(0)" ::: "memory");
  __builtin_amdgcn_sched_barrier(0);
  __builtin_amdgcn_s_barrier();
  __builtin_amdgcn_sched_barrier(0);
  // t = 14 (CUR = 0): write B(15) from set0, stage A(15)
  G2_WRITEB(1, 0);
  __builtin_amdgcn_sched_barrier(0);
  gload16(asrc0 + 480, &As[1][arow0]);
  gload16(asrc1 + 480, &As[1][arow1]);
  __builtin_amdgcn_sched_barrier(0);
  G2_MFMA(0);
  asm volatile("s_waitcnt vmcnt(0) lgkmcnt(0)" ::: "memory");
  __builtin_amdgcn_sched_barrier(0);
  __builtin_amdgcn_s_barrier();
  __builtin_amdgcn_sched_barrier(0);
  // t = 15
  G2_MFMA(1);

#undef G2_STEP
#undef G2_MFMA
#undef G2_WRITEB
#undef G2_LOADB

  // epilogue: + b2 (k-chunk 0 only), scale, atomic scatter-add
  #pragma unroll
  for (int i = 0; i < 4; i++) {
    #pragma unroll
    for (int r = 0; r < 4; r++) {
      const int m = wm*64 + i*16 + quad*4 + r;
      if (m0 + m < nt) {
        const int slot = off + m0 + m;
        const int t    = etok[slot];
        const float s  = escale[slot];
        #pragma unroll
        for (int j = 0; j < 4; j++) {
          const int n = n0 + wn*64 + j*16 + lr;
          float v = acc[i][j][r];
          if (kc == 0) v += b2[e*HDIM + n];
          atomicAdd(&out[(size_t)t*HDIM + n], s * v);
        }
      }
    }
  }
}

extern "C" void kernel_launch(void* const* d_in, const int* in_sizes, int n_in,
                              void* d_out, int out_size, void* d_ws, size_t ws_size,
                              hipStream_t stream) {
  const float* hidden = (const float*)d_in[0];
  const int*   sel    = (const int*)d_in[1];
  const float* scal   = (const float*)d_in[2];
  const float* w1     = (const float*)d_in[3];
  const float* b1     = (const float*)d_in[4];
  const float* w2     = (const float*)d_in[5];
  const float* b2     = (const float*)d_in[6];
  float* out = (float*)d_out;

  char* ws = (char*)d_ws;
  int*    offsets = (int*)(ws + WB_OFFSETS);
  int*    etok    = (int*)(ws + WB_ETOK);
  float*  escale  = (float*)(ws + WB_ESCALE);
  bf16_t* act     = (bf16_t*)(ws + WB_ACT);
  bf16_t* hbf     = (bf16_t*)(ws + WB_H);

  hipMemsetAsync(d_out, 0, (size_t)out_size * sizeof(float), stream);

  route_all<<<1, 256, 0, stream>>>(sel, scal, offsets, etok, escale);
  convert_h<<<(int)(H_ELEMS/8/256), 256, 0, stream>>>(hidden, hbf);

  // gemm1: x = n-tile (32), y = expert (8), z = m-tile (16, mostly dead past 2).
  gemm1_v8<<<dim3(FDIM/64, NEXP, NENT/128), 256, 0, stream>>>(hbf, w1, b1, offsets, etok, act);
  // gemm2: x = n-tile(8) x splitK(4), y = expert, z = m-tile.
  gemm2_v8<<<dim3((HDIM/128)*4, NEXP, NENT/128), 256, 0, stream>>>(act, w2, b2, offsets, etok, escale, out);
}